// Round 9
// baseline (43.674 us; speedup 1.0000x reference)
//
#include <hip/hip_runtime.h>
#include <math.h>

// Problem constants (from setup_inputs)
constexpr int B = 8, N = 65536, C = 80, M = 64;
constexpr int APB = 256;          // anchors per block
constexpr int BPI = N / APB;      // 256 blocks per image
constexpr int K4 = C / 4;         // 20 float4 per anchor row
constexpr float F_ALPHA = 0.25f;
constexpr float F_EPS = 1e-4f;
constexpr float F_BETA = 1.0f / 9.0f;
constexpr float F_LIM = 1.0f - F_EPS;
constexpr float K_NEG = 0.75f * 0.6931471805599453f;  // (1-alpha)*ln2

__device__ __forceinline__ float waveReduceSum(float v) {
    #pragma unroll
    for (int off = 32; off > 0; off >>= 1) v += __shfl_down(v, off, 64);
    return v;
}

// One block = 256 anchors of one image. The focal sweep applies the negative
// formula to EVERY element unconditionally (no code/limit lookup -> fully
// independent of the assignment), interleaved 3-IoU-steps-per-float4 with the
// division-free argmax loop in ONE fused loop (loads hide under IoU VALU, no
// mid-block barrier, no phase convoy). Rare post-loop corrections (linear in
// the block sum): pos anchors swap in the true positive-class term; ignored
// anchors subtract their row's negterm sum (row is L2-hot).
__global__ __launch_bounds__(256) void fused_kernel(
    const float* __restrict__ anchors,   // [N,4]
    const float* __restrict__ regs,      // [B,N,4]
    const float* __restrict__ ann,       // [B,M,5]
    const float* __restrict__ cls,       // [B,N,C]
    float4* __restrict__ partials)       // [B*BPI]
{
    const int b = blockIdx.y;
    const int n0 = blockIdx.x * APB;
    const int tid = threadIdx.x;
    const int wave = tid >> 6, lane = tid & 63;

    __shared__ float4 sbox[M];      // x1,y1,x2,y2
    __shared__ float  sarea[M];     // area, or +inf for invalid GT
    __shared__ float  slab[M];      // label
    __shared__ float  swsum[3][4];

    if (tid < M) {
        const float* a = ann + (size_t)(b * M + tid) * 5;
        const float x1 = a[0], y1 = a[1], x2 = a[2], y2 = a[3], lb = a[4];
        sbox[tid] = make_float4(x1, y1, x2, y2);
        sarea[tid] = (lb != -1.0f) ? (x2 - x1) * (y2 - y1) : __builtin_huge_valf();
        slab[tid] = lb;
    }
    __syncthreads();

    const int n = n0 + tid;
    const float4 av = reinterpret_cast<const float4*>(anchors)[n];
    const float aarea = (av.z - av.x) * (av.w - av.y);

    const float4* __restrict__ cp =
        reinterpret_cast<const float4*>(cls) + ((size_t)b * N + n0) * K4;

    // best IoU as ratio bn/bd; init (-1, 0) sentinel loses to everything.
    float bn = -1.0f, bd = 0.0f;
    int bestj = 0;
    float a0 = 0.0f, a1 = 0.0f, a2 = 0.0f, a3 = 0.0f;

    auto iou_step = [&](int j) {
        const float4 bb = sbox[j];
        const float iw = fmaxf(fminf(av.z, bb.z) - fmaxf(av.x, bb.x), 0.0f);
        const float ih = fmaxf(fminf(av.w, bb.w) - fmaxf(av.y, bb.y), 0.0f);
        const float inter = iw * ih;
        const float ua = fmaxf(aarea + sarea[j] - inter, 1e-8f); // inf if invalid
        // inter/ua > bn/bd <=> inter*bd > bn*ua (dens >= 0; inf auto-loses,
        // NaN (0*inf) compares false = keep)
        const bool take = inter * bd > bn * ua;
        bn = take ? inter : bn;
        bd = take ? ua : bd;
        bestj = take ? j : bestj;
    };

    // ---- fused loop: 20 sweep float4 x 3 IoU steps, then 4-step IoU tail ----
    #pragma unroll 4
    for (int k = 0; k < K4; ++k) {
        const float4 v = cp[k * 256 + tid];      // issue early
        iou_step(3 * k);                         // independent VALU fills latency
        iou_step(3 * k + 1);
        iou_step(3 * k + 2);
        const float vv[4] = {v.x, v.y, v.z, v.w};
        float* accp[4] = {&a0, &a1, &a2, &a3};
        #pragma unroll
        for (int q = 0; q < 4; ++q) {
            const float x = fminf(vv[q], F_LIM); // v >= 0
            *accp[q] = fmaf(x * x, __log2f(1.0f - x), *accp[q]);
        }
    }
    #pragma unroll
    for (int j = 60; j < 64; ++j) iou_step(j);

    const bool pos = bn > 0.5f * bd;   // bd=inf -> false
    const bool neg = bn < 0.4f * bd;   // bd=inf -> true

    // ---- corrections (all linear in the block sum) --------------------------
    float np = 0.0f, rl = 0.0f;
    float corr = 0.0f;    // acc-space terms to REMOVE from the block sum
    float posadd = 0.0f;  // loss-space term to ADD

    if (pos) {
        np = 1.0f;
        const float4 g = sbox[bestj];
        float gw = g.z - g.x, gh = g.w - g.y;
        const float gcx = g.x + 0.5f * gw, gcy = g.y + 0.5f * gh;
        gw = fmaxf(gw, 1.0f);
        gh = fmaxf(gh, 1.0f);
        const float aw = av.z - av.x, ah = av.w - av.y;
        const float acx = av.x + 0.5f * aw, acy = av.y + 0.5f * ah;
        const float t0 = ((gcx - acx) / aw) / 0.1f;
        const float t1 = ((gcy - acy) / ah) / 0.1f;
        const float t2 = logf(gw / aw) / 0.2f;
        const float t3 = logf(gh / ah) / 0.2f;
        const float4 rv = reinterpret_cast<const float4*>(regs)[(size_t)b * N + n];
        const float d0 = fabsf(t0 - rv.x), d1 = fabsf(t1 - rv.y);
        const float d2 = fabsf(t2 - rv.z), d3 = fabsf(t3 - rv.w);
        auto sl1 = [](float d) { return d < F_BETA ? 4.5f * d * d : d - (0.5f / 9.0f); };
        rl = sl1(d0) + sl1(d1) + sl1(d2) + sl1(d3);

        // Swap the sweep's neg-term for the true positive term on (n, code).
        const int code = (int)slab[bestj];
        const float xp = cls[((size_t)b * N + n) * C + code];
        const float xs = fminf(xp, F_LIM);                      // sweep's x
        corr = xs * xs * __log2f(1.0f - xs);                    // remove
        const float xr = fminf(fmaxf(xp, F_EPS), F_LIM);        // ref clamp
        const float om = 1.0f - xr;
        posadd = F_ALPHA * om * om * (-__logf(xr));             // add
    } else if (!neg) {
        // Ignored anchor: remove its whole row's neg-terms (L2-hot re-read).
        const float4* __restrict__ rowp =
            reinterpret_cast<const float4*>(cls) + ((size_t)b * N + n) * K4;
        float c0 = 0.0f, c1 = 0.0f, c2 = 0.0f, c3 = 0.0f;
        #pragma unroll 4
        for (int kk = 0; kk < K4; ++kk) {
            const float4 w = rowp[kk];
            const float ww[4] = {w.x, w.y, w.z, w.w};
            float* ccp[4] = {&c0, &c1, &c2, &c3};
            #pragma unroll
            for (int q = 0; q < 4; ++q) {
                const float x = fminf(ww[q], F_LIM);            // identical to sweep
                *ccp[q] = fmaf(x * x, __log2f(1.0f - x), *ccp[q]);
            }
        }
        corr = (c0 + c1) + (c2 + c3);
    }

    const float cl_t = fmaf(-K_NEG, ((a0 + a1) + (a2 + a3)) - corr, posadd);

    // ---- block reduce, one partial per block --------------------------------
    np = waveReduceSum(np);
    rl = waveReduceSum(rl);
    float cl = waveReduceSum(cl_t);
    if (lane == 0) { swsum[0][wave] = np; swsum[1][wave] = rl; swsum[2][wave] = cl; }
    __syncthreads();
    if (tid == 0) {
        float4 r;
        r.x = swsum[0][0] + swsum[0][1] + swsum[0][2] + swsum[0][3];
        r.y = swsum[1][0] + swsum[1][1] + swsum[1][2] + swsum[1][3];
        r.z = swsum[2][0] + swsum[2][1] + swsum[2][2] + swsum[2][3];
        r.w = 0.0f;
        partials[b * BPI + blockIdx.x] = r;
    }
}

// One wave per image reduces its 256 block-partials, then thread 0 means.
__global__ __launch_bounds__(512) void final_kernel(
    const float4* __restrict__ partials, float* __restrict__ out)
{
    const int wave = threadIdx.x >> 6, lane = threadIdx.x & 63;
    __shared__ float simg[8];

    float np = 0.0f, rl = 0.0f, cl = 0.0f;
    for (int k = lane; k < BPI; k += 64) {
        const float4 p = partials[wave * BPI + k];
        np += p.x; rl += p.y; cl += p.z;
    }
    np = waveReduceSum(np);
    rl = waveReduceSum(rl);
    cl = waveReduceSum(cl);
    if (lane == 0) {
        const float c = cl / fmaxf(np, 1.0f);
        const float r = (np > 0.0f) ? rl / (fmaxf(np, 1.0f) * 4.0f) : 0.0f;
        simg[wave] = c + r;
    }
    __syncthreads();
    if (threadIdx.x == 0) {
        float t = 0.0f;
        #pragma unroll
        for (int b2 = 0; b2 < B; ++b2) t += simg[b2];
        out[0] = t * (1.0f / (float)B);
    }
}

extern "C" void kernel_launch(void* const* d_in, const int* in_sizes, int n_in,
                              void* d_out, int out_size, void* d_ws, size_t ws_size,
                              hipStream_t stream) {
    const float* classifications = (const float*)d_in[0]; // [B,N,C]
    const float* regressions     = (const float*)d_in[1]; // [B,N,4]
    const float* anchors         = (const float*)d_in[2]; // [1,N,4]
    const float* annotations     = (const float*)d_in[3]; // [B,M,5]
    float* out = (float*)d_out;
    float4* partials = (float4*)d_ws;                     // B*BPI = 2048 float4

    dim3 g(BPI, B);
    fused_kernel<<<g, 256, 0, stream>>>(anchors, regressions, annotations,
                                        classifications, partials);
    final_kernel<<<1, 512, 0, stream>>>(partials, out);
}

// Round 10
// 38.201 us; speedup vs baseline: 1.1433x; 1.1433x over previous
//
#include <hip/hip_runtime.h>
#include <math.h>

// Problem constants (from setup_inputs)
constexpr int B = 8, N = 65536, C = 80, M = 64;
constexpr int APB = 256;          // anchors per block (64 per wave)
constexpr int BPI = N / APB;      // 256 blocks per image
constexpr int K4 = C / 4;         // 20 float4 per anchor row
constexpr float F_ALPHA = 0.25f;
constexpr float F_EPS = 1e-4f;
constexpr float F_BETA = 1.0f / 9.0f;
constexpr float F_LIM = 1.0f - F_EPS;
constexpr float K_NEG = 0.75f * 0.6931471805599453f;  // (1-alpha)*ln2

__device__ __forceinline__ float waveReduceSum(float v) {
    #pragma unroll
    for (int off = 32; off > 0; off >>= 1) v += __shfl_down(v, off, 64);
    return v;
}

// One block = 256 anchors (4 INDEPENDENT waves x 64 anchors).
// Prologue: wave 0 ballots+compacts valid GTs (stable order -> argmax
//   first-occurrence preserved; invalid GTs provably never win, so skipping
//   them is exact), pads to x8 with area=+inf sentinels. One barrier.
// Per wave (no further barriers): division-free IoU argmax over Mv_pad GTs,
//   then the negative-formula focal sweep over the wave's OWN 64x80 chunk
//   (contiguous -> coalesced), per-anchor limit via __shfl from the owning
//   lane. lim = 0 kills ignored anchors' terms; pos anchors corrected by a
//   per-lane delta (single element re-read). Waves drift independently ->
//   VALU phase of some waves overlaps the memory phase of others.
__global__ __launch_bounds__(256) void fused_kernel(
    const float* __restrict__ anchors,   // [N,4]
    const float* __restrict__ regs,      // [B,N,4]
    const float* __restrict__ ann,       // [B,M,5]
    const float* __restrict__ cls,       // [B,N,C]
    float4* __restrict__ partials)       // [B*BPI*4], one per wave
{
    const int b = blockIdx.y;
    const int n0 = blockIdx.x * APB;
    const int tid = threadIdx.x;
    const int wave = tid >> 6, lane = tid & 63;

    __shared__ float4 sbox[M + 8];   // compacted valid GTs + pad
    __shared__ float  sarea[M + 8];  // area (+inf for pad)
    __shared__ float  slab[M + 8];   // label
    __shared__ int    sMvPad;

    if (tid < M) {   // wave 0 only (M == 64)
        const float* a = ann + (size_t)(b * M + tid) * 5;
        const float x1 = a[0], y1 = a[1], x2 = a[2], y2 = a[3], lb = a[4];
        const bool valid = (lb != -1.0f);
        const unsigned long long mask = __ballot(valid);
        const int slot = __popcll(mask & ((1ull << lane) - 1ull));
        const int Mv = __popcll(mask);
        if (lane < 8) {              // pad entries: never win (ua = +inf)
            sbox[Mv + lane] = make_float4(0.f, 0.f, 0.f, 0.f);
            sarea[Mv + lane] = __builtin_huge_valf();
            slab[Mv + lane] = -1.0f;
        }
        if (valid) {                 // stable compaction
            sbox[slot] = make_float4(x1, y1, x2, y2);
            sarea[slot] = (x2 - x1) * (y2 - y1);
            slab[slot] = lb;
        }
        if (lane == 0) sMvPad = (Mv + 7) & ~7;
    }
    __syncthreads();                 // the only block-wide barrier
    const int MvPad = sMvPad;

    // ---------------- phase 1: division-free assignment ----------------
    const int n = n0 + tid;
    const float4 av = reinterpret_cast<const float4*>(anchors)[n];
    const float aarea = (av.z - av.x) * (av.w - av.y);

    // best IoU as ratio bn/bd; init (-1, 0) sentinel loses to everything
    // (only survives if Mv == 0 -> loop empty -> neg, matching ref).
    float bn = -1.0f, bd = 0.0f;
    int bestj = 0;
    for (int j0 = 0; j0 < MvPad; j0 += 8) {
        #pragma unroll
        for (int u = 0; u < 8; ++u) {
            const int j = j0 + u;
            const float4 bb = sbox[j];
            const float iw = fmaxf(fminf(av.z, bb.z) - fmaxf(av.x, bb.x), 0.0f);
            const float ih = fmaxf(fminf(av.w, bb.w) - fmaxf(av.y, bb.y), 0.0f);
            const float inter = iw * ih;
            const float ua = fmaxf(aarea + sarea[j] - inter, 1e-8f); // inf: pad
            // inter/ua > bn/bd <=> inter*bd > bn*ua (dens >= 0; pad auto-loses:
            // bn>0 -> rhs inf; bn==0 -> NaN -> false; bn==-1,bd==0 happens only
            // before any valid take, and the first valid j always takes)
            const bool take = inter * bd > bn * ua;
            bn = take ? inter : bn;
            bd = take ? ua : bd;
            bestj = take ? j : bestj;
        }
    }
    const bool pos = bn > 0.5f * bd;
    const bool neg = bn < 0.4f * bd;
    const float limf = (pos || neg) ? F_LIM : 0.0f;   // ignore -> 0 kills terms

    float np = 0.0f, rl = 0.0f, delta = 0.0f;
    if (pos) {
        np = 1.0f;
        const float4 g = sbox[bestj];
        float gw = g.z - g.x, gh = g.w - g.y;
        const float gcx = g.x + 0.5f * gw, gcy = g.y + 0.5f * gh;
        gw = fmaxf(gw, 1.0f);
        gh = fmaxf(gh, 1.0f);
        const float aw = av.z - av.x, ah = av.w - av.y;
        const float acx = av.x + 0.5f * aw, acy = av.y + 0.5f * ah;
        const float t0 = ((gcx - acx) / aw) / 0.1f;
        const float t1 = ((gcy - acy) / ah) / 0.1f;
        const float t2 = logf(gw / aw) / 0.2f;
        const float t3 = logf(gh / ah) / 0.2f;
        const float4 rv = reinterpret_cast<const float4*>(regs)[(size_t)b * N + n];
        const float d0 = fabsf(t0 - rv.x), d1 = fabsf(t1 - rv.y);
        const float d2 = fabsf(t2 - rv.z), d3 = fabsf(t3 - rv.w);
        auto sl1 = [](float d) { return d < F_BETA ? 4.5f * d * d : d - (0.5f / 9.0f); };
        rl = sl1(d0) + sl1(d1) + sl1(d2) + sl1(d3);

        // Swap the sweep's neg-term for the true positive term on (n, code).
        const int code = (int)slab[bestj];
        const float xp = cls[((size_t)b * N + n) * C + code];
        const float x = fminf(fmaxf(xp, F_EPS), F_LIM);
        const float om = 1.0f - x;
        delta = F_ALPHA * om * om * (-__logf(x))
              - (1.0f - F_ALPHA) * x * x * (-__logf(om));
    }

    // ---------------- phase 2: wave-local focal sweep (no barrier) -----------
    // Wave sweeps its OWN 64 anchors' 64x80 floats = 1280 float4, contiguous.
    // acc += x^2 * log2(1-x), x = fmin(v, lim); scaled once by -K_NEG.
    const float4* __restrict__ cpw =
        reinterpret_cast<const float4*>(cls) + ((size_t)b * N + n0 + wave * 64) * K4;
    float a0 = 0.0f, a1 = 0.0f, a2 = 0.0f, a3 = 0.0f;
    #pragma unroll 4
    for (int k = 0; k < K4; ++k) {   // 20 iterations
        const int f = k * 64 + lane;
        const int nl = f / 20;                        // owning lane (0..63)
        const float lim = __shfl(limf, nl, 64);
        const float4 v = cpw[f];
        const float vv[4] = {v.x, v.y, v.z, v.w};
        float* accp[4] = {&a0, &a1, &a2, &a3};
        #pragma unroll
        for (int q = 0; q < 4; ++q) {
            const float x = fminf(vv[q], lim);        // v >= 0; lim=0 -> term 0
            *accp[q] = fmaf(x * x, __log2f(1.0f - x), *accp[q]);
        }
    }
    const float cl_t = fmaf(-K_NEG, (a0 + a1) + (a2 + a3), delta);

    // ---------------- per-wave partial (no end barrier) ----------------------
    np = waveReduceSum(np);
    rl = waveReduceSum(rl);
    float cl = waveReduceSum(cl_t);
    if (lane == 0) {
        partials[(((size_t)b * BPI + blockIdx.x) << 2) | wave] =
            make_float4(np, rl, cl, 0.0f);
    }
}

// One wave per image reduces its 1024 wave-partials, then thread 0 means.
__global__ __launch_bounds__(512) void final_kernel(
    const float4* __restrict__ partials, float* __restrict__ out)
{
    const int wave = threadIdx.x >> 6, lane = threadIdx.x & 63;
    __shared__ float simg[8];
    constexpr int PPI = BPI * 4;   // 1024 partials per image

    float np = 0.0f, rl = 0.0f, cl = 0.0f;
    for (int k = lane; k < PPI; k += 64) {
        const float4 p = partials[wave * PPI + k];
        np += p.x; rl += p.y; cl += p.z;
    }
    np = waveReduceSum(np);
    rl = waveReduceSum(rl);
    cl = waveReduceSum(cl);
    if (lane == 0) {
        const float c = cl / fmaxf(np, 1.0f);
        const float r = (np > 0.0f) ? rl / (fmaxf(np, 1.0f) * 4.0f) : 0.0f;
        simg[wave] = c + r;
    }
    __syncthreads();
    if (threadIdx.x == 0) {
        float t = 0.0f;
        #pragma unroll
        for (int b2 = 0; b2 < B; ++b2) t += simg[b2];
        out[0] = t * (1.0f / (float)B);
    }
}

extern "C" void kernel_launch(void* const* d_in, const int* in_sizes, int n_in,
                              void* d_out, int out_size, void* d_ws, size_t ws_size,
                              hipStream_t stream) {
    const float* classifications = (const float*)d_in[0]; // [B,N,C]
    const float* regressions     = (const float*)d_in[1]; // [B,N,4]
    const float* anchors         = (const float*)d_in[2]; // [1,N,4]
    const float* annotations     = (const float*)d_in[3]; // [B,M,5]
    float* out = (float*)d_out;
    float4* partials = (float4*)d_ws;                     // B*BPI*4 = 8192 float4

    dim3 g(BPI, B);
    fused_kernel<<<g, 256, 0, stream>>>(anchors, regressions, annotations,
                                        classifications, partials);
    final_kernel<<<1, 512, 0, stream>>>(partials, out);
}